// Round 4
// baseline (78597.174 us; speedup 1.0000x reference)
//
#include <hip/hip_runtime.h>
#include <math.h>

typedef __attribute__((ext_vector_type(4))) float f32x4;
typedef __attribute__((ext_vector_type(8))) __bf16 bf16x8;
typedef __attribute__((ext_vector_type(4))) __bf16 bf16x4;
typedef __attribute__((ext_vector_type(4))) unsigned int u32x4;

#define DI __device__ __forceinline__

constexpr int Bd = 2, Sd = 2048, Vd = 32000, Ed = 512, Hd = 1024, MDd = 256, Pd = 4096, Wd = 128;
constexpr int BS = Bd * Sd;          // 4096 rows
constexpr int GBLK = 128;            // GRU persistent blocks

DI float sigmoidf_(float x) { return 1.0f / (1.0f + expf(-x)); }

// ---------------------------------------------------------------------------
// Generic GEMM: C[M,N] = epi( A[M,K] * Wt[N,K]^T + bias )
// EPI 0: C = acc + bias
// EPI 1: C = (relu(acc + bias))^2
// EPI 3: atomicAdd(C[r, untied[c]], acc + (1 + gate[r]*ms) * bias[c])
// ---------------------------------------------------------------------------
template<int EPI>
__global__ __launch_bounds__(256) void gemm_bt(
    const float* __restrict__ A, const float* __restrict__ Wt,
    const float* __restrict__ bias, float* __restrict__ C,
    int M, int N, int K, int ldc,
    const float* __restrict__ gate, const float* __restrict__ msp,
    const int* __restrict__ untied)
{
  __shared__ __bf16 As[128][40];   // +8 pad: 80B row stride, 16B-aligned
  __shared__ __bf16 Bs[128][40];
  const int tid  = threadIdx.x;
  const int lane = tid & 63, wv = tid >> 6;
  const int m0 = blockIdx.y * 128, n0 = blockIdx.x * 128;
  const int wrow = (wv >> 1) * 64, wcol = (wv & 1) * 64;

  f32x4 acc[4][4] = {};

  const int sr  = tid >> 3;          // 0..31
  const int sc4 = (tid & 7) << 2;    // 0..28 step 4
  const int nk  = K >> 5;

  for (int kt = 0; kt < nk; ++kt) {
    const int k0 = kt << 5;
    __syncthreads();
    #pragma unroll
    for (int i = 0; i < 4; ++i) {
      const int r = sr + 32 * i;
      f32x4 av = *reinterpret_cast<const f32x4*>(A  + (size_t)(m0 + r) * K + k0 + sc4);
      f32x4 bv = *reinterpret_cast<const f32x4*>(Wt + (size_t)(n0 + r) * K + k0 + sc4);
      bf16x4 ah, bh;
      ah.x = (__bf16)av.x; ah.y = (__bf16)av.y; ah.z = (__bf16)av.z; ah.w = (__bf16)av.w;
      bh.x = (__bf16)bv.x; bh.y = (__bf16)bv.y; bh.z = (__bf16)bv.z; bh.w = (__bf16)bv.w;
      *reinterpret_cast<bf16x4*>(&As[r][sc4]) = ah;
      *reinterpret_cast<bf16x4*>(&Bs[r][sc4]) = bh;
    }
    __syncthreads();

    bf16x8 af[4], bfr[4];
    #pragma unroll
    for (int t2 = 0; t2 < 4; ++t2) {
      af[t2]  = *reinterpret_cast<const bf16x8*>(&As[wrow + t2 * 16 + (lane & 15)][(lane >> 4) * 8]);
      bfr[t2] = *reinterpret_cast<const bf16x8*>(&Bs[wcol + t2 * 16 + (lane & 15)][(lane >> 4) * 8]);
    }
    #pragma unroll
    for (int mi = 0; mi < 4; ++mi)
      #pragma unroll
      for (int ni = 0; ni < 4; ++ni)
        acc[mi][ni] = __builtin_amdgcn_mfma_f32_16x16x32_bf16(af[mi], bfr[ni], acc[mi][ni], 0, 0, 0);
  }

  const float ms = (EPI == 3) ? msp[0] : 0.f;
  #pragma unroll
  for (int mi = 0; mi < 4; ++mi) {
    #pragma unroll
    for (int ni = 0; ni < 4; ++ni) {
      const int cc = n0 + wcol + ni * 16 + (lane & 15);
      const float bv = bias ? bias[cc] : 0.f;
      #pragma unroll
      for (int rg = 0; rg < 4; ++rg) {
        const int rr = m0 + wrow + mi * 16 + (lane >> 4) * 4 + rg;
        const float v = acc[mi][ni][rg];
        if (EPI == 0) {
          C[(size_t)rr * ldc + cc] = v + bv;
        } else if (EPI == 1) {
          float u = fmaxf(v + bv, 0.f);
          C[(size_t)rr * ldc + cc] = u * u;
        } else {
          float g = 1.f + gate[rr] * ms;
          atomicAdd(&C[(size_t)rr * ldc + untied[cc]], v + g * bv);
        }
      }
    }
  }
}

// sc0 (L1-bypass, L2-hit) 32B poll of 4 consecutive u64 {tag,val} slots.
DI void poll2x16_sc0(const unsigned long long* p, u32x4& a, u32x4& c) {
  unsigned long long ad = (unsigned long long)p;
  asm volatile("global_load_dwordx4 %0, %2, off sc0\n\t"
               "global_load_dwordx4 %1, %2, off offset:16 sc0\n\t"
               "s_waitcnt vmcnt(0)"
               : "=&v"(a), "=&v"(c) : "v"(ad) : "memory");
}

// ---------------------------------------------------------------------------
// Persistent GRU v4: 128 blocks x 512 threads. Wave wv of block bid owns
// h-index j = bid*8+wv for both batches; w_hh rows for j in registers.
// Producers: relaxed agent atomic-store {tag,val} to hb (coherence point).
// ONE relay block per XCD (elected via atomicAdd, XCD id from
// s_getreg(HW_REG_XCC_ID)) polls hb with agent atomic loads (8 pollers
// instead of 128 -> 16x less coherence-point traffic) and republishes into
// a per-XCD staging buffer with PLAIN stores (dirty lines in the local L2).
// Consumers poll staging with sc0 loads: intra-XCD L2 is coherent, so no
// fences needed and no staleness possible. Tags self-validate every read;
// bounded retry falls back to direct hb atomic poll (guaranteed progress
// even if XCD detection misbehaves).
// ---------------------------------------------------------------------------
__global__ __launch_bounds__(512) void gru_kernel(
    const float* __restrict__ gi,    // [BS][3H]
    const float* __restrict__ w_hh,  // [3H][H]
    const float* __restrict__ b_hh,  // [3H]
    float* __restrict__ states,      // [BS][H]
    unsigned long long* __restrict__ hb,       // [2][2*Hd] {tag,val}
    unsigned long long* __restrict__ staging,  // [8][2][2*Hd]
    int* __restrict__ xcdcnt)                  // [8]
{
  __shared__ float hsm[2][Hd];       // [batch][h] = h(t-1)
  __shared__ int s_info;
  const int bid = blockIdx.x, tid = threadIdx.x;
  const int lane = tid & 63, wv = tid >> 6;
  const int j = bid * 8 + wv;

  // --- preload w_hh rows (r,z,n for index j) into registers, lane-sliced ---
  f32x4 wr[4], wz[4], wn[4];
  #pragma unroll
  for (int k4 = 0; k4 < 4; ++k4) {
    const int k = lane * 4 + k4 * 256;
    wr[k4] = *reinterpret_cast<const f32x4*>(w_hh + (size_t)(0 * Hd + j) * Hd + k);
    wz[k4] = *reinterpret_cast<const f32x4*>(w_hh + (size_t)(1 * Hd + j) * Hd + k);
    wn[k4] = *reinterpret_cast<const f32x4*>(w_hh + (size_t)(2 * Hd + j) * Hd + k);
  }
  const float br = b_hh[j], bz = b_hh[Hd + j], bn = b_hh[2 * Hd + j];

  if (tid == 0) {
    unsigned xcc = 0;
    asm volatile("s_getreg_b32 %0, hwreg(HW_REG_XCC_ID)" : "=s"(xcc));
    const int b = (int)(xcc & 7u);
    const int rank = atomicAdd(&xcdcnt[b], 1);
    s_info = b | ((rank == 0) ? 8 : 0);
  }
  for (int i = tid; i < 2 * Hd; i += 512) (&hsm[0][0])[i] = 0.f;
  __syncthreads();
  const int bucket = s_info & 7;
  const bool isrelay = (s_info & 8) != 0;
  unsigned long long* stg = staging + (size_t)bucket * 2 * 2 * Hd;

  // gi prefetch for t=0 (lane 0 only uses them)
  float gir0 = 0, giz0 = 0, gin0 = 0, gir1 = 0, giz1 = 0, gin1 = 0;
  if (lane == 0) {
    const float* g0 = gi;
    const float* g1 = gi + (size_t)Sd * 3 * Hd;
    gir0 = g0[j]; giz0 = g0[Hd + j]; gin0 = g0[2 * Hd + j];
    gir1 = g1[j]; giz1 = g1[Hd + j]; gin1 = g1[2 * Hd + j];
  }

  const int slot0 = tid * 4;         // this thread's 4 slots in [2*Hd]

  for (int t = 0; t < Sd; ++t) {
    // ---- matvec: 6 dot-1024 per wave, weights in regs, h from LDS ----
    float d0 = 0, d1 = 0, d2 = 0, d3 = 0, d4 = 0, d5 = 0;
    #pragma unroll
    for (int k4 = 0; k4 < 4; ++k4) {
      const int k = lane * 4 + k4 * 256;
      f32x4 h0 = *reinterpret_cast<const f32x4*>(&hsm[0][k]);
      f32x4 h1 = *reinterpret_cast<const f32x4*>(&hsm[1][k]);
      d0 += wr[k4].x*h0.x + wr[k4].y*h0.y + wr[k4].z*h0.z + wr[k4].w*h0.w;
      d1 += wz[k4].x*h0.x + wz[k4].y*h0.y + wz[k4].z*h0.z + wz[k4].w*h0.w;
      d2 += wn[k4].x*h0.x + wn[k4].y*h0.y + wn[k4].z*h0.z + wn[k4].w*h0.w;
      d3 += wr[k4].x*h1.x + wr[k4].y*h1.y + wr[k4].z*h1.z + wr[k4].w*h1.w;
      d4 += wz[k4].x*h1.x + wz[k4].y*h1.y + wz[k4].z*h1.z + wz[k4].w*h1.w;
      d5 += wn[k4].x*h1.x + wn[k4].y*h1.y + wn[k4].z*h1.z + wn[k4].w*h1.w;
    }
    #pragma unroll
    for (int off = 32; off > 0; off >>= 1) {
      d0 += __shfl_xor(d0, off, 64);
      d1 += __shfl_xor(d1, off, 64);
      d2 += __shfl_xor(d2, off, 64);
      d3 += __shfl_xor(d3, off, 64);
      d4 += __shfl_xor(d4, off, 64);
      d5 += __shfl_xor(d5, off, 64);
    }
    // all threads done reading hsm for this step before anyone overwrites it
    __syncthreads();

    const unsigned tagu = (unsigned)(t + 1);
    const unsigned long long tag = (unsigned long long)(t + 1);
    const int par = (t + 1) & 1;
    unsigned long long* hbp = hb + (size_t)par * 2 * Hd;
    unsigned long long* stp = stg + (size_t)par * 2 * Hd;

    if (lane == 0) {
      const float ho0 = hsm[0][j], ho1 = hsm[1][j];
      float r0 = sigmoidf_(gir0 + d0 + br);
      float z0 = sigmoidf_(giz0 + d1 + bz);
      float n0 = tanhf(gin0 + r0 * (d2 + bn));
      float hn0 = (1.f - z0) * n0 + z0 * ho0;
      float r1 = sigmoidf_(gir1 + d3 + br);
      float z1 = sigmoidf_(giz1 + d4 + bz);
      float n1 = tanhf(gin1 + r1 * (d5 + bn));
      float hn1 = (1.f - z1) * n1 + z1 * ho1;
      states[(size_t)t * Hd + j] = hn0;
      states[(size_t)(Sd + t) * Hd + j] = hn1;
      unsigned long long p0 = (tag << 32) | (unsigned long long)__float_as_uint(hn0);
      unsigned long long p1 = (tag << 32) | (unsigned long long)__float_as_uint(hn1);
      __hip_atomic_store(&hbp[j],      p0, __ATOMIC_RELAXED, __HIP_MEMORY_SCOPE_AGENT);
      __hip_atomic_store(&hbp[Hd + j], p1, __ATOMIC_RELAXED, __HIP_MEMORY_SCOPE_AGENT);
      // prefetch gi for t+1 (overlaps the poll below)
      const int tn = (t + 1 < Sd) ? (t + 1) : t;
      const float* g0 = gi + (size_t)tn * 3 * Hd;
      const float* g1 = gi + (size_t)(Sd + tn) * 3 * Hd;
      gir0 = g0[j]; giz0 = g0[Hd + j]; gin0 = g0[2 * Hd + j];
      gir1 = g1[j]; giz1 = g1[Hd + j]; gin1 = g1[2 * Hd + j];
    }

    if (t + 1 < Sd) {
      float v0 = 0, v1 = 0, v2 = 0, v3 = 0;
      if (isrelay) {
        // ---- relay: atomic poll of hb; republish into local-L2 staging ----
        bool f0 = false, f1 = false, f2 = false, f3 = false;
        do {
          unsigned long long x0, x1, x2, x3;
          if (!f0) x0 = __hip_atomic_load(&hbp[slot0 + 0], __ATOMIC_RELAXED, __HIP_MEMORY_SCOPE_AGENT);
          if (!f1) x1 = __hip_atomic_load(&hbp[slot0 + 1], __ATOMIC_RELAXED, __HIP_MEMORY_SCOPE_AGENT);
          if (!f2) x2 = __hip_atomic_load(&hbp[slot0 + 2], __ATOMIC_RELAXED, __HIP_MEMORY_SCOPE_AGENT);
          if (!f3) x3 = __hip_atomic_load(&hbp[slot0 + 3], __ATOMIC_RELAXED, __HIP_MEMORY_SCOPE_AGENT);
          if (!f0 && (x0 >> 32) == tag) { stp[slot0 + 0] = x0; v0 = __uint_as_float((unsigned)x0); f0 = true; }
          if (!f1 && (x1 >> 32) == tag) { stp[slot0 + 1] = x1; v1 = __uint_as_float((unsigned)x1); f1 = true; }
          if (!f2 && (x2 >> 32) == tag) { stp[slot0 + 2] = x2; v2 = __uint_as_float((unsigned)x2); f2 = true; }
          if (!f3 && (x3 >> 32) == tag) { stp[slot0 + 3] = x3; v3 = __uint_as_float((unsigned)x3); f3 = true; }
        } while (!(f0 && f1 && f2 && f3));
      } else {
        // ---- consumer: sc0 poll of local-L2 staging (no fences needed) ----
        bool done = false;
        for (int rounds = 0; rounds < 256 && !done; ++rounds) {
          u32x4 a, c;
          poll2x16_sc0(&stp[slot0], a, c);
          if (a[1] == tagu && a[3] == tagu && c[1] == tagu && c[3] == tagu) {
            v0 = __uint_as_float(a[0]); v1 = __uint_as_float(a[2]);
            v2 = __uint_as_float(c[0]); v3 = __uint_as_float(c[2]);
            done = true;
          }
        }
        if (!done) {
          // guaranteed-progress fallback: direct atomic poll of hb
          bool f0 = false, f1 = false, f2 = false, f3 = false;
          do {
            unsigned long long x0, x1, x2, x3;
            if (!f0) x0 = __hip_atomic_load(&hbp[slot0 + 0], __ATOMIC_RELAXED, __HIP_MEMORY_SCOPE_AGENT);
            if (!f1) x1 = __hip_atomic_load(&hbp[slot0 + 1], __ATOMIC_RELAXED, __HIP_MEMORY_SCOPE_AGENT);
            if (!f2) x2 = __hip_atomic_load(&hbp[slot0 + 2], __ATOMIC_RELAXED, __HIP_MEMORY_SCOPE_AGENT);
            if (!f3) x3 = __hip_atomic_load(&hbp[slot0 + 3], __ATOMIC_RELAXED, __HIP_MEMORY_SCOPE_AGENT);
            if (!f0 && (x0 >> 32) == tag) { v0 = __uint_as_float((unsigned)x0); f0 = true; }
            if (!f1 && (x1 >> 32) == tag) { v1 = __uint_as_float((unsigned)x1); f1 = true; }
            if (!f2 && (x2 >> 32) == tag) { v2 = __uint_as_float((unsigned)x2); f2 = true; }
            if (!f3 && (x3 >> 32) == tag) { v3 = __uint_as_float((unsigned)x3); f3 = true; }
          } while (!(f0 && f1 && f2 && f3));
        }
      }
      (&hsm[0][0])[slot0 + 0] = v0;
      (&hsm[0][0])[slot0 + 1] = v1;
      (&hsm[0][0])[slot0 + 2] = v2;
      (&hsm[0][0])[slot0 + 3] = v3;
    }
    __syncthreads();
  }
}

// ---------------------------------------------------------------------------
__global__ __launch_bounds__(128) void embed_kernel(
    const int* __restrict__ ids, const float* __restrict__ emb, float* __restrict__ x)
{
  const int row = blockIdx.x;
  const int tok = ids[row];
  reinterpret_cast<f32x4*>(x)[(size_t)row * (Ed / 4) + threadIdx.x] =
      reinterpret_cast<const f32x4*>(emb)[(size_t)tok * (Ed / 4) + threadIdx.x];
}

__global__ __launch_bounds__(256) void gate_kernel(
    const float* __restrict__ states, const float* __restrict__ wg,
    const float* __restrict__ bg, float* __restrict__ gate)
{
  const int row = blockIdx.x * 4 + (threadIdx.x >> 6);
  const int lane = threadIdx.x & 63;
  float s = 0;
  for (int k = lane; k < Hd; k += 64) s += states[(size_t)row * Hd + k] * wg[k];
  #pragma unroll
  for (int off = 32; off > 0; off >>= 1) s += __shfl_down(s, off, 64);
  if (lane == 0) gate[row] = sigmoidf_(s + bg[0]);
}

__global__ __launch_bounds__(256) void attn_kernel(
    const float* __restrict__ q, const float* __restrict__ k,
    const float* __restrict__ v, float* __restrict__ ctx)
{
  const int row = blockIdx.x;
  const int b = row >> 11, qi = row & (Sd - 1);
  const int tid = threadIdx.x, lane = tid & 63, wv = tid >> 6;
  __shared__ float qs[MDd];
  __shared__ float sc[Wd];
  qs[tid] = q[(size_t)row * MDd + tid];
  __syncthreads();
  const int lo = (qi > Wd) ? (qi - Wd) : 0;
  const int len = qi - lo;
  for (int jj = wv; jj < len; jj += 4) {
    const float* kr = k + (size_t)(b * Sd + lo + jj) * MDd;
    f32x4 kv = *reinterpret_cast<const f32x4*>(kr + lane * 4);
    f32x4 qv = *reinterpret_cast<const f32x4*>(&qs[lane * 4]);
    float s = kv.x * qv.x + kv.y * qv.y + kv.z * qv.z + kv.w * qv.w;
    #pragma unroll
    for (int off = 32; off > 0; off >>= 1) s += __shfl_down(s, off, 64);
    if (lane == 0) sc[jj] = s * 0.0625f;
  }
  __syncthreads();
  if (wv == 0 && len > 0) {
    float m = -3.4e38f;
    for (int jj = lane; jj < len; jj += 64) m = fmaxf(m, sc[jj]);
    #pragma unroll
    for (int off = 32; off > 0; off >>= 1) m = fmaxf(m, __shfl_xor(m, off, 64));
    float ssum = 0;
    for (int jj = lane; jj < len; jj += 64) { float e = expf(sc[jj] - m); sc[jj] = e; ssum += e; }
    #pragma unroll
    for (int off = 32; off > 0; off >>= 1) ssum += __shfl_xor(ssum, off, 64);
    const float inv = 1.f / ssum;
    for (int jj = lane; jj < len; jj += 64) sc[jj] *= inv;
  }
  __syncthreads();
  #pragma unroll
  for (int e0 = 0; e0 < Ed; e0 += 256) {
    const int e = e0 + tid;
    float a = 0;
    for (int jj = 0; jj < len; ++jj)
      a += sc[jj] * v[(size_t)(b * Sd + lo + jj) * Ed + e];
    ctx[(size_t)row * Ed + e] = a;
  }
}

__global__ __launch_bounds__(256) void fuse_kernel(
    float* __restrict__ bf, const float* __restrict__ ctx,
    const float* __restrict__ gate, const float* __restrict__ msp)
{
  const size_t i = (size_t)blockIdx.x * 256 + threadIdx.x;
  const int r = (int)(i >> 9);
  bf[i] += gate[r] * msp[0] * ctx[i];
}

// ---------------------------------------------------------------------------
extern "C" void kernel_launch(void* const* d_in, const int* in_sizes, int n_in,
                              void* d_out, int out_size, void* d_ws, size_t ws_size,
                              hipStream_t stream)
{
  const int*   ids    = (const int*)d_in[0];
  const int*   untied = (const int*)d_in[1];
  const float* emb    = (const float*)d_in[2];
  const float* w_ih   = (const float*)d_in[3];
  const float* w_hh   = (const float*)d_in[4];
  const float* b_ih   = (const float*)d_in[5];
  const float* b_hh   = (const float*)d_in[6];
  const float* wq     = (const float*)d_in[7];
  const float* bq     = (const float*)d_in[8];
  const float* wk     = (const float*)d_in[9];
  const float* bk     = (const float*)d_in[10];
  const float* wv     = (const float*)d_in[11];
  const float* bv     = (const float*)d_in[12];
  const float* wg     = (const float*)d_in[13];
  const float* bg     = (const float*)d_in[14];
  const float* w_fc   = (const float*)d_in[15];
  const float* b_fc   = (const float*)d_in[16];
  const float* w_hp   = (const float*)d_in[17];
  const float* b_hp   = (const float*)d_in[18];
  const float* out_b  = (const float*)d_in[19];
  const float* w_ph   = (const float*)d_in[20];
  const float* b_ph   = (const float*)d_in[21];
  const float* msc    = (const float*)d_in[22];
  float* out = (float*)d_out;

  float* ws      = (float*)d_ws;
  float* gi      = ws;                               // [BS][3H]
  float* states  = gi + (size_t)BS * 3 * Hd;         // [BS][H]
  float* featb   = states + (size_t)BS * Hd;         // x, then base_feat [BS][E]
  float* hfb     = featb + (size_t)BS * Ed;          // hf [BS][4E], later q/k/v/ctx/gate
  unsigned long long* hb      = (unsigned long long*)(hfb + (size_t)BS * 4 * Ed); // [2][2H]
  unsigned long long* staging = hb + 2 * 2 * Hd;     // [8][2][2H]
  int* xcdcnt = (int*)(staging + 8 * 2 * 2 * Hd);    // [8]

  float* qb    = hfb;
  float* kb    = qb + (size_t)BS * MDd;
  float* vb    = kb + (size_t)BS * MDd;
  float* ctxb  = vb + (size_t)BS * Ed;
  float* gateb = ctxb + (size_t)BS * Ed;

  hipMemsetAsync(hb, 0, (2 * 2 * Hd + 8 * 2 * 2 * Hd) * sizeof(unsigned long long)
                        + 8 * sizeof(int), stream);

  // x = emb[ids]
  embed_kernel<<<BS, 128, 0, stream>>>(ids, emb, featb);
  // gi = x @ w_ih^T + b_ih
  gemm_bt<0><<<dim3(3 * Hd / 128, BS / 128), 256, 0, stream>>>(
      featb, w_ih, b_ih, gi, BS, 3 * Hd, Ed, 3 * Hd, nullptr, nullptr, nullptr);
  // states = GRU(gi)
  gru_kernel<<<GBLK, 512, 0, stream>>>(gi, w_hh, b_hh, states, hb, staging, xcdcnt);
  // hf = relu(states @ w_fc^T + b_fc)^2
  gemm_bt<1><<<dim3(4 * Ed / 128, BS / 128), 256, 0, stream>>>(
      states, w_fc, b_fc, hfb, BS, 4 * Ed, Hd, 4 * Ed, nullptr, nullptr, nullptr);
  // base_feat = hf @ w_hp^T + b_hp
  gemm_bt<0><<<dim3(Ed / 128, BS / 128), 256, 0, stream>>>(
      hfb, w_hp, b_hp, featb, BS, Ed, 4 * Ed, Ed, nullptr, nullptr, nullptr);
  // base_logits = base_feat @ emb^T + out_bias  -> d_out
  gemm_bt<0><<<dim3(Vd / 128, BS / 128), 256, 0, stream>>>(
      featb, emb, out_b, out, BS, Vd, Ed, Vd, nullptr, nullptr, nullptr);
  // q,k,v
  gemm_bt<0><<<dim3(MDd / 128, BS / 128), 256, 0, stream>>>(
      states, wq, bq, qb, BS, MDd, Hd, MDd, nullptr, nullptr, nullptr);
  gemm_bt<0><<<dim3(MDd / 128, BS / 128), 256, 0, stream>>>(
      states, wk, bk, kb, BS, MDd, Hd, MDd, nullptr, nullptr, nullptr);
  gemm_bt<0><<<dim3(Ed / 128, BS / 128), 256, 0, stream>>>(
      states, wv, bv, vb, BS, Ed, Hd, Ed, nullptr, nullptr, nullptr);
  // gate
  gate_kernel<<<BS / 4, 256, 0, stream>>>(states, wg, bg, gateb);
  // ctx = windowed attention
  attn_kernel<<<BS, 256, 0, stream>>>(qb, kb, vb, ctxb);
  // base_feat += gate * ms * ctx   (in place)
  fuse_kernel<<<(BS * Ed) / 256, 256, 0, stream>>>(featb, ctxb, gateb, msc);
  // scatter: d_out[r, untied[c]] += fused_feat @ w_ph^T + (1+gate*ms)*b_ph
  gemm_bt<3><<<dim3(Pd / 128, BS / 128), 256, 0, stream>>>(
      featb, w_ph, b_ph, out, BS, Pd, Ed, Vd, gateb, msc, untied);
}

// Round 5
// 11938.021 us; speedup vs baseline: 6.5838x; 6.5838x over previous
//
#include <hip/hip_runtime.h>
#include <math.h>

typedef __attribute__((ext_vector_type(4))) float f32x4;
typedef __attribute__((ext_vector_type(8))) __bf16 bf16x8;
typedef __attribute__((ext_vector_type(4))) __bf16 bf16x4;
typedef __attribute__((ext_vector_type(4))) unsigned int u32x4;

#define DI __device__ __forceinline__

constexpr int Bd = 2, Sd = 2048, Vd = 32000, Ed = 512, Hd = 1024, MDd = 256, Pd = 4096, Wd = 128;
constexpr int BS = Bd * Sd;          // 4096 rows
constexpr int GBLK = 128;            // GRU persistent blocks

DI float sigmoidf_(float x) { return 1.0f / (1.0f + expf(-x)); }

// ---------------------------------------------------------------------------
// Generic GEMM: C[M,N] = epi( A[M,K] * Wt[N,K]^T + bias )
// EPI 0: C = acc + bias
// EPI 1: C = (relu(acc + bias))^2
// EPI 3: atomicAdd(C[r, untied[c]], acc + (1 + gate[r]*ms) * bias[c])
// ---------------------------------------------------------------------------
template<int EPI>
__global__ __launch_bounds__(256) void gemm_bt(
    const float* __restrict__ A, const float* __restrict__ Wt,
    const float* __restrict__ bias, float* __restrict__ C,
    int M, int N, int K, int ldc,
    const float* __restrict__ gate, const float* __restrict__ msp,
    const int* __restrict__ untied)
{
  __shared__ __bf16 As[128][40];   // +8 pad: 80B row stride, 16B-aligned
  __shared__ __bf16 Bs[128][40];
  const int tid  = threadIdx.x;
  const int lane = tid & 63, wv = tid >> 6;
  const int m0 = blockIdx.y * 128, n0 = blockIdx.x * 128;
  const int wrow = (wv >> 1) * 64, wcol = (wv & 1) * 64;

  f32x4 acc[4][4] = {};

  const int sr  = tid >> 3;          // 0..31
  const int sc4 = (tid & 7) << 2;    // 0..28 step 4
  const int nk  = K >> 5;

  for (int kt = 0; kt < nk; ++kt) {
    const int k0 = kt << 5;
    __syncthreads();
    #pragma unroll
    for (int i = 0; i < 4; ++i) {
      const int r = sr + 32 * i;
      f32x4 av = *reinterpret_cast<const f32x4*>(A  + (size_t)(m0 + r) * K + k0 + sc4);
      f32x4 bv = *reinterpret_cast<const f32x4*>(Wt + (size_t)(n0 + r) * K + k0 + sc4);
      bf16x4 ah, bh;
      ah.x = (__bf16)av.x; ah.y = (__bf16)av.y; ah.z = (__bf16)av.z; ah.w = (__bf16)av.w;
      bh.x = (__bf16)bv.x; bh.y = (__bf16)bv.y; bh.z = (__bf16)bv.z; bh.w = (__bf16)bv.w;
      *reinterpret_cast<bf16x4*>(&As[r][sc4]) = ah;
      *reinterpret_cast<bf16x4*>(&Bs[r][sc4]) = bh;
    }
    __syncthreads();

    bf16x8 af[4], bfr[4];
    #pragma unroll
    for (int t2 = 0; t2 < 4; ++t2) {
      af[t2]  = *reinterpret_cast<const bf16x8*>(&As[wrow + t2 * 16 + (lane & 15)][(lane >> 4) * 8]);
      bfr[t2] = *reinterpret_cast<const bf16x8*>(&Bs[wcol + t2 * 16 + (lane & 15)][(lane >> 4) * 8]);
    }
    #pragma unroll
    for (int mi = 0; mi < 4; ++mi)
      #pragma unroll
      for (int ni = 0; ni < 4; ++ni)
        acc[mi][ni] = __builtin_amdgcn_mfma_f32_16x16x32_bf16(af[mi], bfr[ni], acc[mi][ni], 0, 0, 0);
  }

  const float ms = (EPI == 3) ? msp[0] : 0.f;
  #pragma unroll
  for (int mi = 0; mi < 4; ++mi) {
    #pragma unroll
    for (int ni = 0; ni < 4; ++ni) {
      const int cc = n0 + wcol + ni * 16 + (lane & 15);
      const float bv = bias ? bias[cc] : 0.f;
      #pragma unroll
      for (int rg = 0; rg < 4; ++rg) {
        const int rr = m0 + wrow + mi * 16 + (lane >> 4) * 4 + rg;
        const float v = acc[mi][ni][rg];
        if (EPI == 0) {
          C[(size_t)rr * ldc + cc] = v + bv;
        } else if (EPI == 1) {
          float u = fmaxf(v + bv, 0.f);
          C[(size_t)rr * ldc + cc] = u * u;
        } else {
          float g = 1.f + gate[rr] * ms;
          atomicAdd(&C[(size_t)rr * ldc + untied[cc]], v + g * bv);
        }
      }
    }
  }
}

// Device-coherent 32B poll: sc0 (L1 bypass) + sc1 (L2 bypass) -> reads the
// same coherence point the producers' relaxed agent atomic stores land at.
// No fences, no invalidates. Each u64 {tag,val} is internally consistent.
DI void poll4_coherent(const unsigned long long* p, u32x4& a, u32x4& c) {
  asm volatile("global_load_dwordx4 %0, %2, off sc0 sc1\n\t"
               "global_load_dwordx4 %1, %2, off offset:16 sc0 sc1\n\t"
               "s_waitcnt vmcnt(0)"
               : "=&v"(a), "=&v"(c) : "v"(p) : "memory");
}

// ---------------------------------------------------------------------------
// Persistent GRU v5: 128 blocks x 512 threads. Wave wv of block bid owns
// h-index j = bid*8+wv for both batches; w_hh rows for j in registers.
// Producers publish {tag,val} via relaxed agent atomic stores (hb first,
// bulky states stores after). Consumers poll hb with WIDE device-coherent
// loads (global_load_dwordx4 sc0 sc1): half the op count of the 8B atomic
// poll, same coherence point, self-validating tags, parity double-buffer.
// Bounded rounds + atomic-load fallback guarantee progress regardless.
// ---------------------------------------------------------------------------
__global__ __launch_bounds__(512) void gru_kernel(
    const float* __restrict__ gi,    // [BS][3H]
    const float* __restrict__ w_hh,  // [3H][H]
    const float* __restrict__ b_hh,  // [3H]
    float* __restrict__ states,      // [BS][H]
    unsigned long long* __restrict__ hb)  // [2][2*Hd] packed {tag,val}
{
  __shared__ float hsm[2][Hd];       // [batch][h] = h(t-1)
  const int bid = blockIdx.x, tid = threadIdx.x;
  const int lane = tid & 63, wv = tid >> 6;
  const int j = bid * 8 + wv;

  // --- preload w_hh rows (r,z,n for index j) into registers, lane-sliced ---
  f32x4 wr[4], wz[4], wn[4];
  #pragma unroll
  for (int k4 = 0; k4 < 4; ++k4) {
    const int k = lane * 4 + k4 * 256;
    wr[k4] = *reinterpret_cast<const f32x4*>(w_hh + (size_t)(0 * Hd + j) * Hd + k);
    wz[k4] = *reinterpret_cast<const f32x4*>(w_hh + (size_t)(1 * Hd + j) * Hd + k);
    wn[k4] = *reinterpret_cast<const f32x4*>(w_hh + (size_t)(2 * Hd + j) * Hd + k);
  }
  const float br = b_hh[j], bz = b_hh[Hd + j], bn = b_hh[2 * Hd + j];

  for (int i = tid; i < 2 * Hd; i += 512) (&hsm[0][0])[i] = 0.f;
  __syncthreads();

  // gi prefetch for t=0 (lane 0 only uses them)
  float gir0 = 0, giz0 = 0, gin0 = 0, gir1 = 0, giz1 = 0, gin1 = 0;
  if (lane == 0) {
    const float* g0 = gi;
    const float* g1 = gi + (size_t)Sd * 3 * Hd;
    gir0 = g0[j]; giz0 = g0[Hd + j]; gin0 = g0[2 * Hd + j];
    gir1 = g1[j]; giz1 = g1[Hd + j]; gin1 = g1[2 * Hd + j];
  }

  const int slot0 = tid * 4;         // this thread's 4 poll slots in [2*Hd]

  for (int t = 0; t < Sd; ++t) {
    // ---- matvec: 6 dot-1024 per wave, weights in regs, h from LDS ----
    float d0 = 0, d1 = 0, d2 = 0, d3 = 0, d4 = 0, d5 = 0;
    #pragma unroll
    for (int k4 = 0; k4 < 4; ++k4) {
      const int k = lane * 4 + k4 * 256;
      f32x4 h0 = *reinterpret_cast<const f32x4*>(&hsm[0][k]);
      f32x4 h1 = *reinterpret_cast<const f32x4*>(&hsm[1][k]);
      d0 += wr[k4].x*h0.x + wr[k4].y*h0.y + wr[k4].z*h0.z + wr[k4].w*h0.w;
      d1 += wz[k4].x*h0.x + wz[k4].y*h0.y + wz[k4].z*h0.z + wz[k4].w*h0.w;
      d2 += wn[k4].x*h0.x + wn[k4].y*h0.y + wn[k4].z*h0.z + wn[k4].w*h0.w;
      d3 += wr[k4].x*h1.x + wr[k4].y*h1.y + wr[k4].z*h1.z + wr[k4].w*h1.w;
      d4 += wz[k4].x*h1.x + wz[k4].y*h1.y + wz[k4].z*h1.z + wz[k4].w*h1.w;
      d5 += wn[k4].x*h1.x + wn[k4].y*h1.y + wn[k4].z*h1.z + wn[k4].w*h1.w;
    }
    #pragma unroll
    for (int off = 32; off > 0; off >>= 1) {
      d0 += __shfl_xor(d0, off, 64);
      d1 += __shfl_xor(d1, off, 64);
      d2 += __shfl_xor(d2, off, 64);
      d3 += __shfl_xor(d3, off, 64);
      d4 += __shfl_xor(d4, off, 64);
      d5 += __shfl_xor(d5, off, 64);
    }
    // all threads done reading hsm for this step before anyone overwrites it
    __syncthreads();

    const unsigned tagu = (unsigned)(t + 1);
    const unsigned long long tag = (unsigned long long)(t + 1);
    const int par = (t + 1) & 1;
    unsigned long long* hbp = hb + (size_t)par * 2 * Hd;

    if (lane == 0) {
      const float ho0 = hsm[0][j], ho1 = hsm[1][j];
      float r0 = sigmoidf_(gir0 + d0 + br);
      float z0 = sigmoidf_(giz0 + d1 + bz);
      float n0 = tanhf(gin0 + r0 * (d2 + bn));
      float hn0 = (1.f - z0) * n0 + z0 * ho0;
      float r1 = sigmoidf_(gir1 + d3 + br);
      float z1 = sigmoidf_(giz1 + d4 + bz);
      float n1 = tanhf(gin1 + r1 * (d5 + bn));
      float hn1 = (1.f - z1) * n1 + z1 * ho1;
      // publish FIRST (release is tag-in-data), bulky states stores after
      unsigned long long p0 = (tag << 32) | (unsigned long long)__float_as_uint(hn0);
      unsigned long long p1 = (tag << 32) | (unsigned long long)__float_as_uint(hn1);
      __hip_atomic_store(&hbp[j],      p0, __ATOMIC_RELAXED, __HIP_MEMORY_SCOPE_AGENT);
      __hip_atomic_store(&hbp[Hd + j], p1, __ATOMIC_RELAXED, __HIP_MEMORY_SCOPE_AGENT);
      states[(size_t)t * Hd + j] = hn0;
      states[(size_t)(Sd + t) * Hd + j] = hn1;
      // prefetch gi for t+1 (overlaps the poll below)
      const int tn = (t + 1 < Sd) ? (t + 1) : t;
      const float* g0 = gi + (size_t)tn * 3 * Hd;
      const float* g1 = gi + (size_t)(Sd + tn) * 3 * Hd;
      gir0 = g0[j]; giz0 = g0[Hd + j]; gin0 = g0[2 * Hd + j];
      gir1 = g1[j]; giz1 = g1[Hd + j]; gin1 = g1[2 * Hd + j];
    }

    if (t + 1 < Sd) {
      float v0 = 0, v1 = 0, v2 = 0, v3 = 0;
      bool done = false;
      for (int rounds = 0; rounds < 4096 && !done; ++rounds) {
        u32x4 a, c;
        poll4_coherent(&hbp[slot0], a, c);
        if (a[1] == tagu && a[3] == tagu && c[1] == tagu && c[3] == tagu) {
          v0 = __uint_as_float(a[0]); v1 = __uint_as_float(a[2]);
          v2 = __uint_as_float(c[0]); v3 = __uint_as_float(c[2]);
          done = true;
        } else if (rounds >= 4) {
          __builtin_amdgcn_s_sleep(1);   // pace stragglers, cut fabric hammering
        }
      }
      if (!done) {
        // guaranteed-progress fallback: 8B atomic loads (proven in round 2)
        bool f0 = false, f1 = false, f2 = false, f3 = false;
        do {
          unsigned long long x0, x1, x2, x3;
          if (!f0) x0 = __hip_atomic_load(&hbp[slot0 + 0], __ATOMIC_RELAXED, __HIP_MEMORY_SCOPE_AGENT);
          if (!f1) x1 = __hip_atomic_load(&hbp[slot0 + 1], __ATOMIC_RELAXED, __HIP_MEMORY_SCOPE_AGENT);
          if (!f2) x2 = __hip_atomic_load(&hbp[slot0 + 2], __ATOMIC_RELAXED, __HIP_MEMORY_SCOPE_AGENT);
          if (!f3) x3 = __hip_atomic_load(&hbp[slot0 + 3], __ATOMIC_RELAXED, __HIP_MEMORY_SCOPE_AGENT);
          if (!f0 && (x0 >> 32) == tag) { v0 = __uint_as_float((unsigned)x0); f0 = true; }
          if (!f1 && (x1 >> 32) == tag) { v1 = __uint_as_float((unsigned)x1); f1 = true; }
          if (!f2 && (x2 >> 32) == tag) { v2 = __uint_as_float((unsigned)x2); f2 = true; }
          if (!f3 && (x3 >> 32) == tag) { v3 = __uint_as_float((unsigned)x3); f3 = true; }
        } while (!(f0 && f1 && f2 && f3));
      }
      (&hsm[0][0])[slot0 + 0] = v0;
      (&hsm[0][0])[slot0 + 1] = v1;
      (&hsm[0][0])[slot0 + 2] = v2;
      (&hsm[0][0])[slot0 + 3] = v3;
    }
    __syncthreads();
  }
}

// ---------------------------------------------------------------------------
__global__ __launch_bounds__(128) void embed_kernel(
    const int* __restrict__ ids, const float* __restrict__ emb, float* __restrict__ x)
{
  const int row = blockIdx.x;
  const int tok = ids[row];
  reinterpret_cast<f32x4*>(x)[(size_t)row * (Ed / 4) + threadIdx.x] =
      reinterpret_cast<const f32x4*>(emb)[(size_t)tok * (Ed / 4) + threadIdx.x];
}

__global__ __launch_bounds__(256) void gate_kernel(
    const float* __restrict__ states, const float* __restrict__ wg,
    const float* __restrict__ bg, float* __restrict__ gate)
{
  const int row = blockIdx.x * 4 + (threadIdx.x >> 6);
  const int lane = threadIdx.x & 63;
  float s = 0;
  for (int k = lane; k < Hd; k += 64) s += states[(size_t)row * Hd + k] * wg[k];
  #pragma unroll
  for (int off = 32; off > 0; off >>= 1) s += __shfl_down(s, off, 64);
  if (lane == 0) gate[row] = sigmoidf_(s + bg[0]);
}

__global__ __launch_bounds__(256) void attn_kernel(
    const float* __restrict__ q, const float* __restrict__ k,
    const float* __restrict__ v, float* __restrict__ ctx)
{
  const int row = blockIdx.x;
  const int b = row >> 11, qi = row & (Sd - 1);
  const int tid = threadIdx.x, lane = tid & 63, wv = tid >> 6;
  __shared__ float qs[MDd];
  __shared__ float sc[Wd];
  qs[tid] = q[(size_t)row * MDd + tid];
  __syncthreads();
  const int lo = (qi > Wd) ? (qi - Wd) : 0;
  const int len = qi - lo;
  for (int jj = wv; jj < len; jj += 4) {
    const float* kr = k + (size_t)(b * Sd + lo + jj) * MDd;
    f32x4 kv = *reinterpret_cast<const f32x4*>(kr + lane * 4);
    f32x4 qv = *reinterpret_cast<const f32x4*>(&qs[lane * 4]);
    float s = kv.x * qv.x + kv.y * qv.y + kv.z * qv.z + kv.w * qv.w;
    #pragma unroll
    for (int off = 32; off > 0; off >>= 1) s += __shfl_down(s, off, 64);
    if (lane == 0) sc[jj] = s * 0.0625f;
  }
  __syncthreads();
  if (wv == 0 && len > 0) {
    float m = -3.4e38f;
    for (int jj = lane; jj < len; jj += 64) m = fmaxf(m, sc[jj]);
    #pragma unroll
    for (int off = 32; off > 0; off >>= 1) m = fmaxf(m, __shfl_xor(m, off, 64));
    float ssum = 0;
    for (int jj = lane; jj < len; jj += 64) { float e = expf(sc[jj] - m); sc[jj] = e; ssum += e; }
    #pragma unroll
    for (int off = 32; off > 0; off >>= 1) ssum += __shfl_xor(ssum, off, 64);
    const float inv = 1.f / ssum;
    for (int jj = lane; jj < len; jj += 64) sc[jj] *= inv;
  }
  __syncthreads();
  #pragma unroll
  for (int e0 = 0; e0 < Ed; e0 += 256) {
    const int e = e0 + tid;
    float a = 0;
    for (int jj = 0; jj < len; ++jj)
      a += sc[jj] * v[(size_t)(b * Sd + lo + jj) * Ed + e];
    ctx[(size_t)row * Ed + e] = a;
  }
}

__global__ __launch_bounds__(256) void fuse_kernel(
    float* __restrict__ bf, const float* __restrict__ ctx,
    const float* __restrict__ gate, const float* __restrict__ msp)
{
  const size_t i = (size_t)blockIdx.x * 256 + threadIdx.x;
  const int r = (int)(i >> 9);
  bf[i] += gate[r] * msp[0] * ctx[i];
}

// ---------------------------------------------------------------------------
extern "C" void kernel_launch(void* const* d_in, const int* in_sizes, int n_in,
                              void* d_out, int out_size, void* d_ws, size_t ws_size,
                              hipStream_t stream)
{
  const int*   ids    = (const int*)d_in[0];
  const int*   untied = (const int*)d_in[1];
  const float* emb    = (const float*)d_in[2];
  const float* w_ih   = (const float*)d_in[3];
  const float* w_hh   = (const float*)d_in[4];
  const float* b_ih   = (const float*)d_in[5];
  const float* b_hh   = (const float*)d_in[6];
  const float* wq     = (const float*)d_in[7];
  const float* bq     = (const float*)d_in[8];
  const float* wk     = (const float*)d_in[9];
  const float* bk     = (const float*)d_in[10];
  const float* wv     = (const float*)d_in[11];
  const float* bv     = (const float*)d_in[12];
  const float* wg     = (const float*)d_in[13];
  const float* bg     = (const float*)d_in[14];
  const float* w_fc   = (const float*)d_in[15];
  const float* b_fc   = (const float*)d_in[16];
  const float* w_hp   = (const float*)d_in[17];
  const float* b_hp   = (const float*)d_in[18];
  const float* out_b  = (const float*)d_in[19];
  const float* w_ph   = (const float*)d_in[20];
  const float* b_ph   = (const float*)d_in[21];
  const float* msc    = (const float*)d_in[22];
  float* out = (float*)d_out;

  float* ws      = (float*)d_ws;
  float* gi      = ws;                               // [BS][3H]
  float* states  = gi + (size_t)BS * 3 * Hd;         // [BS][H]
  float* featb   = states + (size_t)BS * Hd;         // x, then base_feat [BS][E]
  float* hfb     = featb + (size_t)BS * Ed;          // hf [BS][4E], later q/k/v/ctx/gate
  unsigned long long* hb = (unsigned long long*)(hfb + (size_t)BS * 4 * Ed); // [2][2H]

  float* qb    = hfb;
  float* kb    = qb + (size_t)BS * MDd;
  float* vb    = kb + (size_t)BS * MDd;
  float* ctxb  = vb + (size_t)BS * Ed;
  float* gateb = ctxb + (size_t)BS * Ed;

  hipMemsetAsync(hb, 0, 2 * 2 * Hd * sizeof(unsigned long long), stream);

  // x = emb[ids]
  embed_kernel<<<BS, 128, 0, stream>>>(ids, emb, featb);
  // gi = x @ w_ih^T + b_ih
  gemm_bt<0><<<dim3(3 * Hd / 128, BS / 128), 256, 0, stream>>>(
      featb, w_ih, b_ih, gi, BS, 3 * Hd, Ed, 3 * Hd, nullptr, nullptr, nullptr);
  // states = GRU(gi)
  gru_kernel<<<GBLK, 512, 0, stream>>>(gi, w_hh, b_hh, states, hb);
  // hf = relu(states @ w_fc^T + b_fc)^2
  gemm_bt<1><<<dim3(4 * Ed / 128, BS / 128), 256, 0, stream>>>(
      states, w_fc, b_fc, hfb, BS, 4 * Ed, Hd, 4 * Ed, nullptr, nullptr, nullptr);
  // base_feat = hf @ w_hp^T + b_hp
  gemm_bt<0><<<dim3(Ed / 128, BS / 128), 256, 0, stream>>>(
      hfb, w_hp, b_hp, featb, BS, Ed, 4 * Ed, Ed, nullptr, nullptr, nullptr);
  // base_logits = base_feat @ emb^T + out_bias  -> d_out
  gemm_bt<0><<<dim3(Vd / 128, BS / 128), 256, 0, stream>>>(
      featb, emb, out_b, out, BS, Vd, Ed, Vd, nullptr, nullptr, nullptr);
  // q,k,v
  gemm_bt<0><<<dim3(MDd / 128, BS / 128), 256, 0, stream>>>(
      states, wq, bq, qb, BS, MDd, Hd, MDd, nullptr, nullptr, nullptr);
  gemm_bt<0><<<dim3(MDd / 128, BS / 128), 256, 0, stream>>>(
      states, wk, bk, kb, BS, MDd, Hd, MDd, nullptr, nullptr, nullptr);
  gemm_bt<0><<<dim3(Ed / 128, BS / 128), 256, 0, stream>>>(
      states, wv, bv, vb, BS, Ed, Hd, Ed, nullptr, nullptr, nullptr);
  // gate
  gate_kernel<<<BS / 4, 256, 0, stream>>>(states, wg, bg, gateb);
  // ctx = windowed attention
  attn_kernel<<<BS, 256, 0, stream>>>(qb, kb, vb, ctxb);
  // base_feat += gate * ms * ctx   (in place)
  fuse_kernel<<<(BS * Ed) / 256, 256, 0, stream>>>(featb, ctxb, gateb, msc);
  // scatter: d_out[r, untied[c]] += fused_feat @ w_ph^T + (1+gate*ms)*b_ph
  gemm_bt<3><<<dim3(Pd / 128, BS / 128), 256, 0, stream>>>(
      featb, w_ph, b_ph, out, BS, Pd, Ed, Vd, gateb, msc, untied);
}